// Round 7
// baseline (1044.709 us; speedup 1.0000x reference)
//
#include <hip/hip_runtime.h>

#define BB 16
#define HH 512
#define ROWLEN 1536   // W*C
#define KK 51
#define RR 25

// chunk-level XOR swizzle (involution): spreads strided chunk patterns over
// all 8 bank groups; bijective (only low 3 bits change).
__device__ __forceinline__ int sq(int q) { return q ^ ((q >> 3) & 7); }

// ---------------- K0: reduce 2D kernel to 1D weights (g[i] = row sum) -------
__global__ void k_weights(const float* __restrict__ k2d, float* __restrict__ g) {
    int i = threadIdx.x;
    if (i < KK) {
        float s = 0.f;
        for (int j = 0; j < KK; ++j) s += k2d[i * KK + j];
        g[i] = s;
    }
}

// ---------------- H-pass: 51-tap conv along w, flat-space ------------------
// out[f] = sum_j g[j] * in[f + 3*(j-25)] (f = 3w+c). 4 rows/block, 384
// threads = 4 rows x 96 strips of 16 consecutive flat outputs. LDS row:
// 76 pad | 1536 | 76 pad, chunk-swizzled; e = f + 76. Load = straight float4
// copy (no de-interleave). Compute: 42 ds_read_b128/thread; element at
// rel = 4v+mm-76 feeds acc[k] for k ≡ rel (mod 3), |rel-k| <= 75 (<=6 accs,
// all compile-time): 816 FMAs. Store: 4 coalesced float4.
#define HROW 1696    // floats per row-plane = 424 chunks (multiple of 8)
template<bool U8>
__global__ __launch_bounds__(384, 6) void k_hconv(const void* __restrict__ srcv,
                                                  float* __restrict__ dst,
                                                  const float* __restrict__ gsrc) {
    __shared__ __align__(16) float pl[4 * HROW];
    const int t = threadIdx.x;
    const int row0 = blockIdx.x * 4;             // first of 4 rows (b*512+h)

    float gw[KK];
    #pragma unroll
    for (int i = 0; i < KK; ++i) gw[i] = gsrc[i];   // uniform -> scalar regs

    // ---- load 4 rows into swizzled LDS (straight copy) ----
    if (U8) {
        const int r = t / 96, s = t % 96;            // 16 bytes per thread
        const uint4 d = *(const uint4*)((const unsigned char*)srcv
                          + (size_t)(row0 + r) * ROWLEN + 16 * s);
        const unsigned int w4[4] = {d.x, d.y, d.z, d.w};
        float* rowp = &pl[r * HROW];
        #pragma unroll
        for (int cq = 0; cq < 4; ++cq) {
            const unsigned int wd = w4[cq];
            float4 f;
            f.x = (float)(wd & 0xffu);         f.y = (float)((wd >> 8) & 0xffu);
            f.z = (float)((wd >> 16) & 0xffu); f.w = (float)((wd >> 24) & 0xffu);
            *(float4*)&rowp[4 * sq(19 + 4 * s + cq)] = f;
        }
    } else {
        #pragma unroll
        for (int i = 0; i < 4; ++i) {
            const int m = t + 384 * i;               // chunk id 0..1535
            const int r = m / 384, cc = m % 384;
            const float4 f = *(const float4*)((const float*)srcv
                               + (size_t)(row0 + r) * ROWLEN + 4 * cc);
            *(float4*)&pl[r * HROW + 4 * sq(19 + cc)] = f;
        }
    }
    __syncthreads();

    // ---- reflect halos: w=-j <-> w=j, w=511+j <-> 511-j (j=1..25), per c ---
    #pragma unroll
    for (int it = 0; it < 2; ++it) {
        const int item = t + it * 384;
        if (item < 600) {
            const int r = item / 150, k = item % 150;
            float* rowp = &pl[r * HROW];
            int ed, es;
            if (k < 75) {
                const int j = k / 3 + 1, c = k % 3;
                ed = 76 - 3 * j + c;  es = 76 + 3 * j + c;
            } else {
                const int k2 = k - 75;
                const int j = k2 / 3 + 1, c = k2 % 3;
                ed = 1609 + 3 * j + c;  es = 1609 - 3 * j + c;
            }
            rowp[4 * sq(ed >> 2) + (ed & 3)] = rowp[4 * sq(es >> 2) + (es & 3)];
        }
    }
    __syncthreads();

    // ---- compute: 16 consecutive flat outputs per thread ----
    const int r = t / 96, s = t % 96;                // strip f0 = 16*s
    const float* rp = &pl[r * HROW];
    float acc[16];
    #pragma unroll
    for (int k = 0; k < 16; ++k) acc[k] = 0.f;
    #pragma unroll
    for (int v = 0; v < 42; ++v) {                   // chunks q = 4s+v
        const float4 v4 = *(const float4*)&rp[4 * sq(4 * s + v)];
        #pragma unroll
        for (int mm = 0; mm < 4; ++mm) {
            const int rel = 4 * v + mm - 76;         // flat offset from f0
            const float val = (&v4.x)[mm];
            #pragma unroll
            for (int k = ((rel % 3) + 3) % 3; k < 16; k += 3) {
                const int j = (rel + 75 - k) / 3;    // tap index, compile-time
                if (j >= 0 && j < KK) acc[k] += gw[j] * val;
            }
        }
    }
    const size_t ob = (size_t)(row0 + r) * ROWLEN + 16 * s;
    #pragma unroll
    for (int k = 0; k < 4; ++k) {
        float4 o;
        o.x = acc[4*k]; o.y = acc[4*k+1]; o.z = acc[4*k+2]; o.w = acc[4*k+3];
        *(float4*)&dst[ob + 4 * k] = o;
    }
}

// ---------------- V-pass: 51-tap conv along h + fused epilogue --------------
// Tile: 64 flat cols x 128 output rows (+50 halo). 256 threads = 16 col-groups
// (4 cols each, float4) x 16 row-groups (8 rows each): 32 outputs/thread, one
// b128 row-read feeds 4 col-accumulators for up to 8 rows.
// MODE 0: blur -> blurio (d_out as scratch), mask -> mask8.
// MODE 1: soft-mask; read img + blur (from blurio), write final to blurio.
#define FW 64
#define HC 128
#define VROWS 178    // HC + 2*RR

template<int MODE>
__global__ __launch_bounds__(256) void k_vconv(const float* __restrict__ src,
                                               const float* __restrict__ img,
                                               float* blurio,
                                               unsigned char* __restrict__ mask8,
                                               const float* __restrict__ gsrc) {
    __shared__ __align__(16) float tile[VROWS * FW];
    const int t  = threadIdx.x;
    const int cg = t & 15;               // col group: cols 4*cg..4*cg+3
    const int rg = t >> 4;               // row group: rows rg*8..rg*8+7
    const int bid = blockIdx.x;
    const int wcB = bid % 24;
    const int hB  = (bid / 24) & 3;
    const int b   = bid / 96;
    const int wc0 = wcB * 64;
    const int h0  = hB * HC;

    float gw[KK];
    #pragma unroll
    for (int i = 0; i < KK; ++i) gw[i] = gsrc[i];

    const size_t imgbase = (size_t)b * HH * ROWLEN;

    // ---- load tile (178 rows x 16 chunks) with reflect on h ----
    #pragma unroll
    for (int i = 0; i < 12; ++i) {
        const int m = t + 256 * i;
        if (m < VROWS * 16) {
            const int r = m >> 4, cc = m & 15;
            int hs = h0 - RR + r;
            hs = hs < 0 ? -hs : hs;
            hs = hs > 511 ? 1022 - hs : hs;
            *(float4*)&tile[r * FW + 4 * cc] =
                *(const float4*)&src[imgbase + (size_t)hs * ROWLEN + wc0 + 4 * cc];
        }
    }
    __syncthreads();

    float acc[8][4];
    #pragma unroll
    for (int a = 0; a < 8; ++a)
        #pragma unroll
        for (int m = 0; m < 4; ++m) acc[a][m] = 0.f;

    const float* base = &tile[(rg * 8) * FW + 4 * cg];
    #pragma unroll
    for (int jj = 0; jj < 58; ++jj) {
        const float4 v4 = *(const float4*)(base + jj * FW);
        #pragma unroll
        for (int a = 0; a < 8; ++a) {
            const int tap = jj - a;
            if (tap >= 0 && tap < KK) {
                acc[a][0] += gw[tap] * v4.x;
                acc[a][1] += gw[tap] * v4.y;
                acc[a][2] += gw[tap] * v4.z;
                acc[a][3] += gw[tap] * v4.w;
            }
        }
    }

    // ---- fused epilogue ----
    #pragma unroll
    for (int a = 0; a < 8; ++a) {
        const int hh = h0 + rg * 8 + a;
        const size_t idx = imgbase + (size_t)hh * ROWLEN + wc0 + 4 * cg;
        const float4 x4 = *(const float4*)&img[idx];
        if (MODE == 0) {
            float4 bl;
            bl.x = acc[a][0]; bl.y = acc[a][1]; bl.z = acc[a][2]; bl.w = acc[a][3];
            *(float4*)&blurio[idx] = bl;
            unsigned int mw = 0;
            mw |= (fabsf(x4.x - bl.x) * 255.0f > 10.0f) ? 1u : 0u;
            mw |= (fabsf(x4.y - bl.y) * 255.0f > 10.0f) ? (1u << 8) : 0u;
            mw |= (fabsf(x4.z - bl.z) * 255.0f > 10.0f) ? (1u << 16) : 0u;
            mw |= (fabsf(x4.w - bl.w) * 255.0f > 10.0f) ? (1u << 24) : 0u;
            *(unsigned int*)&mask8[idx] = mw;
        } else {
            const float4 bl4 = *(const float4*)&blurio[idx];
            float4 o;
            const float* xp = &x4.x; const float* bp = &bl4.x; float* op = &o.x;
            #pragma unroll
            for (int m = 0; m < 4; ++m) {
                const float x = xp[m];
                const float sharp = fminf(fmaxf(x + 0.5f * (x - bp[m]), 0.f), 1.f);
                op[m] = x + acc[a][m] * (sharp - x);
            }
            *(float4*)&blurio[idx] = o;
        }
    }
}

// ---------------------------------------------------------------------------
extern "C" void kernel_launch(void* const* d_in, const int* in_sizes, int n_in,
                              void* d_out, int out_size, void* d_ws, size_t ws_size,
                              hipStream_t stream) {
    (void)in_sizes; (void)n_in; (void)out_size; (void)ws_size;
    const float* img = (const float*)d_in[0];
    const float* k2d = (const float*)d_in[1];
    float* out = (float*)d_out;

    char* ws = (char*)d_ws;
    float* g = (float*)ws;                                       // 51 floats
    float* tbuf = (float*)(ws + 256);                            // 50.33 MB
    unsigned char* mask8 =
        (unsigned char*)(ws + 256 + (size_t)BB * HH * ROWLEN * 4); // 12.58 MB

    const int nhblk = BB * HH / 4;        // 2048
    const int nvblk = BB * 4 * 24;        // 1536

    k_weights<<<1, 64, 0, stream>>>(k2d, g);
    // P1: H-blur img -> tbuf
    k_hconv<false><<<nhblk, 384, 0, stream>>>((const void*)img, tbuf, g);
    // P2: V-blur tbuf -> blur (into d_out) + mask8
    k_vconv<0><<<nvblk, 256, 0, stream>>>(tbuf, img, out, mask8, g);
    // P3: H-blur mask8 -> tbuf
    k_hconv<true><<<nhblk, 384, 0, stream>>>((const void*)mask8, tbuf, g);
    // P4: V-blur tbuf -> soft mask, fused blend -> d_out
    k_vconv<1><<<nvblk, 256, 0, stream>>>(tbuf, img, out, mask8, g);
}

// Round 8
// 119.081 us; speedup vs baseline: 8.7731x; 8.7731x over previous
//
#include <hip/hip_runtime.h>

#define BB 16
#define HH 512
#define ROWLEN 1536   // W*C
#define KK 51
#define RR 25

// chunk-level XOR swizzle (involution): spreads strided chunk patterns over
// all 8 bank groups; bijective (only low 3 bits change).
__device__ __forceinline__ int sq(int q) { return q ^ ((q >> 3) & 7); }

// ---------------- K0: reduce 2D kernel to 1D weights (g[i] = row sum) -------
__global__ void k_weights(const float* __restrict__ k2d, float* __restrict__ g) {
    int i = threadIdx.x;
    if (i < KK) {
        float s = 0.f;
        for (int j = 0; j < KK; ++j) s += k2d[i * KK + j];
        g[i] = s;
    }
}

// ---------------- H-pass: 51-tap conv along w, per channel ------------------
// 4 rows/block, 512 threads = 4 rows x 128 lanes. Thread owns 4 pixels x 3
// channels = 12 consecutive flat outputs. Plane element e = w+28 (per row,
// channel), chunk-swizzled: addr = plane*576 + 4*sq(e>>2) + (e&3).
// Load: 12 consecutive floats -> register transpose -> 3 aligned b128 LDS
// writes at chunk sq(7+l), lane-chunk-stride 1 (conflict floor).
// Compute: 3 planes x 15 b128 reads (chunks l..l+14); value mm of chunk l+v
// feeds acc[c][a] with tap jj = 4v+mm-a-3 (guard compile-time): 612 FMAs.
// Store: 3 contiguous float4 (flats 12l..12l+11).
#define PSTR 576     // floats per plane = 144 chunks (multiple of 8)
template<bool U8>
__global__ __launch_bounds__(512, 4) void k_hconv(const void* __restrict__ srcv,
                                                  float* __restrict__ dst,
                                                  const float* __restrict__ gsrc) {
    __shared__ __align__(16) float pl[12 * PSTR];
    const int t = threadIdx.x;
    const int row0 = blockIdx.x * 4;             // first of 4 rows (b*512+h)

    float gw[KK];
    #pragma unroll
    for (int i = 0; i < KK; ++i) gw[i] = gsrc[i];   // uniform -> scalar regs

    const int r = t >> 7;             // row 0..3
    const int l = t & 127;            // lane group; pixels w0 = 4l..4l+3
    const size_t rb = (size_t)(row0 + r) * ROWLEN;

    // ---- load 12 consecutive flats, register-transpose into 3 planes ----
    {
        float f[12];
        if (U8) {
            const unsigned char* s8 = (const unsigned char*)srcv + rb + 12 * l;
            unsigned int ww[3];
            ww[0] = *(const unsigned int*)(s8);
            ww[1] = *(const unsigned int*)(s8 + 4);
            ww[2] = *(const unsigned int*)(s8 + 8);
            #pragma unroll
            for (int k = 0; k < 12; ++k)
                f[k] = (float)((ww[k >> 2] >> ((k & 3) * 8)) & 0xffu);
        } else {
            const float* sf = (const float*)srcv + rb + 12 * l;
            *(float4*)&f[0] = *(const float4*)(sf);
            *(float4*)&f[4] = *(const float4*)(sf + 4);
            *(float4*)&f[8] = *(const float4*)(sf + 8);
        }
        const int q = sq(7 + l);                 // chunk of e = 28+4l
        #pragma unroll
        for (int c = 0; c < 3; ++c) {
            float4 o;
            o.x = f[c]; o.y = f[3 + c]; o.z = f[6 + c]; o.w = f[9 + c];
            *(float4*)&pl[(r * 3 + c) * PSTR + 4 * q] = o;
        }
    }
    __syncthreads();

    // ---- reflect halos (np.pad 'reflect'): 12 planes x 50 elements ----
    #pragma unroll
    for (int it = 0; it < 2; ++it) {
        const int item = t + it * 512;
        if (item < 600) {
            const int p = item / 50, k = item % 50;
            int ed, es;
            if (k < 25) { const int j = k + 1;  ed = 28 - j;  es = 28 + j; }
            else        { const int j = k - 24; ed = 539 + j; es = 539 - j; }
            float* pb = &pl[p * PSTR];
            pb[4 * sq(ed >> 2) + (ed & 3)] = pb[4 * sq(es >> 2) + (es & 3)];
        }
    }
    __syncthreads();

    // ---- compute: acc[c][a] = channel c, pixel w0+a ----
    float acc[3][4];
    #pragma unroll
    for (int c = 0; c < 3; ++c)
        #pragma unroll
        for (int a = 0; a < 4; ++a) acc[c][a] = 0.f;

    #pragma unroll
    for (int c = 0; c < 3; ++c) {
        const float* pb = &pl[(r * 3 + c) * PSTR];
        #pragma unroll
        for (int v = 0; v < 15; ++v) {
            const float4 v4 = *(const float4*)&pb[4 * sq(l + v)];
            #pragma unroll
            for (int mm = 0; mm < 4; ++mm) {
                const float val = (&v4.x)[mm];
                #pragma unroll
                for (int a = 0; a < 4; ++a) {
                    const int jj = 4 * v + mm - a - 3;   // tap, compile-time
                    if (jj >= 0 && jj < KK) acc[c][a] += gw[jj] * val;
                }
            }
        }
    }

    // ---- store: 12 consecutive flats = 3 coalesced float4 ----
    float ov[12];
    #pragma unroll
    for (int a = 0; a < 4; ++a)
        #pragma unroll
        for (int c = 0; c < 3; ++c) ov[3 * a + c] = acc[c][a];
    #pragma unroll
    for (int k = 0; k < 3; ++k) {
        float4 o;
        o.x = ov[4*k]; o.y = ov[4*k+1]; o.z = ov[4*k+2]; o.w = ov[4*k+3];
        *(float4*)&dst[rb + 12 * l + 4 * k] = o;
    }
}

// ---------------- V-pass: 51-tap conv along h + fused epilogue --------------
// Tile: 64 flat cols x 128 output rows (+50 halo). 256 threads = 16 col-groups
// (4 cols each, float4) x 16 row-groups (8 rows each): 32 outputs/thread, one
// b128 row-read feeds 4 col-accumulators for up to 8 rows.
// MODE 0: blur -> blurio (d_out as scratch), mask -> mask8.
// MODE 1: soft-mask; read img + blur (from blurio), write final to blurio.
#define FW 64
#define HC 128
#define VROWS 178    // HC + 2*RR

template<int MODE>
__global__ __launch_bounds__(256) void k_vconv(const float* __restrict__ src,
                                               const float* __restrict__ img,
                                               float* blurio,
                                               unsigned char* __restrict__ mask8,
                                               const float* __restrict__ gsrc) {
    __shared__ __align__(16) float tile[VROWS * FW];
    const int t  = threadIdx.x;
    const int cg = t & 15;               // col group: cols 4*cg..4*cg+3
    const int rg = t >> 4;               // row group: rows rg*8..rg*8+7
    const int bid = blockIdx.x;
    const int wcB = bid % 24;
    const int hB  = (bid / 24) & 3;
    const int b   = bid / 96;
    const int wc0 = wcB * 64;
    const int h0  = hB * HC;

    float gw[KK];
    #pragma unroll
    for (int i = 0; i < KK; ++i) gw[i] = gsrc[i];

    const size_t imgbase = (size_t)b * HH * ROWLEN;

    // ---- load tile (178 rows x 16 chunks) with reflect on h ----
    #pragma unroll
    for (int i = 0; i < 12; ++i) {
        const int m = t + 256 * i;
        if (m < VROWS * 16) {
            const int r = m >> 4, cc = m & 15;
            int hs = h0 - RR + r;
            hs = hs < 0 ? -hs : hs;
            hs = hs > 511 ? 1022 - hs : hs;
            *(float4*)&tile[r * FW + 4 * cc] =
                *(const float4*)&src[imgbase + (size_t)hs * ROWLEN + wc0 + 4 * cc];
        }
    }
    __syncthreads();

    float acc[8][4];
    #pragma unroll
    for (int a = 0; a < 8; ++a)
        #pragma unroll
        for (int m = 0; m < 4; ++m) acc[a][m] = 0.f;

    const float* base = &tile[(rg * 8) * FW + 4 * cg];
    #pragma unroll
    for (int jj = 0; jj < 58; ++jj) {
        const float4 v4 = *(const float4*)(base + jj * FW);
        #pragma unroll
        for (int a = 0; a < 8; ++a) {
            const int tap = jj - a;
            if (tap >= 0 && tap < KK) {
                acc[a][0] += gw[tap] * v4.x;
                acc[a][1] += gw[tap] * v4.y;
                acc[a][2] += gw[tap] * v4.z;
                acc[a][3] += gw[tap] * v4.w;
            }
        }
    }

    // ---- fused epilogue ----
    #pragma unroll
    for (int a = 0; a < 8; ++a) {
        const int hh = h0 + rg * 8 + a;
        const size_t idx = imgbase + (size_t)hh * ROWLEN + wc0 + 4 * cg;
        const float4 x4 = *(const float4*)&img[idx];
        if (MODE == 0) {
            float4 bl;
            bl.x = acc[a][0]; bl.y = acc[a][1]; bl.z = acc[a][2]; bl.w = acc[a][3];
            *(float4*)&blurio[idx] = bl;
            unsigned int mw = 0;
            mw |= (fabsf(x4.x - bl.x) * 255.0f > 10.0f) ? 1u : 0u;
            mw |= (fabsf(x4.y - bl.y) * 255.0f > 10.0f) ? (1u << 8) : 0u;
            mw |= (fabsf(x4.z - bl.z) * 255.0f > 10.0f) ? (1u << 16) : 0u;
            mw |= (fabsf(x4.w - bl.w) * 255.0f > 10.0f) ? (1u << 24) : 0u;
            *(unsigned int*)&mask8[idx] = mw;
        } else {
            const float4 bl4 = *(const float4*)&blurio[idx];
            float4 o;
            const float* xp = &x4.x; const float* bp = &bl4.x; float* op = &o.x;
            #pragma unroll
            for (int m = 0; m < 4; ++m) {
                const float x = xp[m];
                const float sharp = fminf(fmaxf(x + 0.5f * (x - bp[m]), 0.f), 1.f);
                op[m] = x + acc[a][m] * (sharp - x);
            }
            *(float4*)&blurio[idx] = o;
        }
    }
}

// ---------------------------------------------------------------------------
extern "C" void kernel_launch(void* const* d_in, const int* in_sizes, int n_in,
                              void* d_out, int out_size, void* d_ws, size_t ws_size,
                              hipStream_t stream) {
    (void)in_sizes; (void)n_in; (void)out_size; (void)ws_size;
    const float* img = (const float*)d_in[0];
    const float* k2d = (const float*)d_in[1];
    float* out = (float*)d_out;

    char* ws = (char*)d_ws;
    float* g = (float*)ws;                                       // 51 floats
    float* tbuf = (float*)(ws + 256);                            // 50.33 MB
    unsigned char* mask8 =
        (unsigned char*)(ws + 256 + (size_t)BB * HH * ROWLEN * 4); // 12.58 MB

    const int nhblk = BB * HH / 4;        // 2048
    const int nvblk = BB * 4 * 24;        // 1536

    k_weights<<<1, 64, 0, stream>>>(k2d, g);
    // P1: H-blur img -> tbuf
    k_hconv<false><<<nhblk, 512, 0, stream>>>((const void*)img, tbuf, g);
    // P2: V-blur tbuf -> blur (into d_out) + mask8
    k_vconv<0><<<nvblk, 256, 0, stream>>>(tbuf, img, out, mask8, g);
    // P3: H-blur mask8 -> tbuf
    k_hconv<true><<<nhblk, 512, 0, stream>>>((const void*)mask8, tbuf, g);
    // P4: V-blur tbuf -> soft mask, fused blend -> d_out
    k_vconv<1><<<nvblk, 256, 0, stream>>>(tbuf, img, out, mask8, g);
}

// Round 9
// 109.505 us; speedup vs baseline: 9.5403x; 1.0875x over previous
//
#include <hip/hip_runtime.h>
#include <hip/hip_fp16.h>

#define BB 16
#define HH 512
#define ROWLEN 1536   // W*C
#define KK 51
#define RR 25

// chunk-level XOR swizzle (involution): spreads strided chunk patterns over
// all 8 bank groups; bijective (only low 3 bits change).
__device__ __forceinline__ int sq(int q) { return q ^ ((q >> 3) & 7); }

// ---------------- K0: reduce 2D kernel to 1D weights (g[i] = row sum) -------
__global__ void k_weights(const float* __restrict__ k2d, float* __restrict__ g) {
    int i = threadIdx.x;
    if (i < KK) {
        float s = 0.f;
        for (int j = 0; j < KK; ++j) s += k2d[i * KK + j];
        g[i] = s;
    }
}

// ---------------- H-pass: 51-tap conv along w, per channel ------------------
// 4 rows/block, 512 threads = 4 rows x 128 lanes. Thread owns 4 pixels x 3
// channels = 12 consecutive flat outputs. Plane element e = w+28, chunk-
// swizzled: addr = plane*576 + 4*sq(e>>2) + (e&3). Compute guard structure
// (proven R5/R8): innermost constant-bound acc loop, compile-time affine
// guard -> 612 FMAs, fully static. Output: fp16, 3 coalesced uint2/thread.
#define PSTR 576     // floats per plane = 144 chunks (multiple of 8)
template<bool U8>
__global__ __launch_bounds__(512, 4) void k_hconv(const void* __restrict__ srcv,
                                                  __half* __restrict__ dst,
                                                  const float* __restrict__ gsrc) {
    __shared__ __align__(16) float pl[12 * PSTR];
    const int t = threadIdx.x;
    const int row0 = blockIdx.x * 4;             // first of 4 rows (b*512+h)

    float gw[KK];
    #pragma unroll
    for (int i = 0; i < KK; ++i) gw[i] = gsrc[i];   // uniform -> scalar regs

    const int r = t >> 7;             // row 0..3
    const int l = t & 127;            // lane group; pixels w0 = 4l..4l+3
    const size_t rb = (size_t)(row0 + r) * ROWLEN;

    // ---- load 12 consecutive flats, register-transpose into 3 planes ----
    {
        float f[12];
        if (U8) {
            const unsigned char* s8 = (const unsigned char*)srcv + rb + 12 * l;
            unsigned int ww[3];
            ww[0] = *(const unsigned int*)(s8);
            ww[1] = *(const unsigned int*)(s8 + 4);
            ww[2] = *(const unsigned int*)(s8 + 8);
            #pragma unroll
            for (int k = 0; k < 12; ++k)
                f[k] = (float)((ww[k >> 2] >> ((k & 3) * 8)) & 0xffu);
        } else {
            const float* sf = (const float*)srcv + rb + 12 * l;
            *(float4*)&f[0] = *(const float4*)(sf);
            *(float4*)&f[4] = *(const float4*)(sf + 4);
            *(float4*)&f[8] = *(const float4*)(sf + 8);
        }
        const int q = sq(7 + l);                 // chunk of e = 28+4l
        #pragma unroll
        for (int c = 0; c < 3; ++c) {
            float4 o;
            o.x = f[c]; o.y = f[3 + c]; o.z = f[6 + c]; o.w = f[9 + c];
            *(float4*)&pl[(r * 3 + c) * PSTR + 4 * q] = o;
        }
    }
    __syncthreads();

    // ---- reflect halos (np.pad 'reflect'): 12 planes x 50 elements ----
    #pragma unroll
    for (int it = 0; it < 2; ++it) {
        const int item = t + it * 512;
        if (item < 600) {
            const int p = item / 50, k = item % 50;
            int ed, es;
            if (k < 25) { const int j = k + 1;  ed = 28 - j;  es = 28 + j; }
            else        { const int j = k - 24; ed = 539 + j; es = 539 - j; }
            float* pb = &pl[p * PSTR];
            pb[4 * sq(ed >> 2) + (ed & 3)] = pb[4 * sq(es >> 2) + (es & 3)];
        }
    }
    __syncthreads();

    // ---- compute: acc[c][a] = channel c, pixel w0+a ----
    float acc[3][4];
    #pragma unroll
    for (int c = 0; c < 3; ++c)
        #pragma unroll
        for (int a = 0; a < 4; ++a) acc[c][a] = 0.f;

    #pragma unroll
    for (int c = 0; c < 3; ++c) {
        const float* pb = &pl[(r * 3 + c) * PSTR];
        #pragma unroll
        for (int v = 0; v < 15; ++v) {
            const float4 v4 = *(const float4*)&pb[4 * sq(l + v)];
            #pragma unroll
            for (int mm = 0; mm < 4; ++mm) {
                const float val = (&v4.x)[mm];
                #pragma unroll
                for (int a = 0; a < 4; ++a) {
                    const int jj = 4 * v + mm - a - 3;   // tap, compile-time
                    if (jj >= 0 && jj < KK) acc[c][a] += gw[jj] * val;
                }
            }
        }
    }

    // ---- store: 12 consecutive fp16 flats = 3 coalesced uint2 ----
    union { __half h[12]; uint2 u2[3]; } pk;
    #pragma unroll
    for (int a = 0; a < 4; ++a)
        #pragma unroll
        for (int c = 0; c < 3; ++c) pk.h[3 * a + c] = __float2half_rn(acc[c][a]);
    uint2* dp = (uint2*)(dst + rb + 12 * l);
    dp[0] = pk.u2[0]; dp[1] = pk.u2[1]; dp[2] = pk.u2[2];
}

// ---------------- V-pass: 51-tap conv along h + fused epilogue --------------
// Tile: 64 flat cols x 128 output rows (+50 halo), f32 in LDS (converted from
// fp16 src on load; uint2/thread, chunk map conflict-free). 256 threads = 16
// col-groups x 16 row-groups; 32 outputs/thread via b128 row-reads.
// MODE 0: v-blur tbuf -> blur (regs only); sharp=clip(img+0.5(img-blur)) ->
//         sharp16 (fp16), mask -> mask8. blur is never written to memory.
// MODE 1: v-blur tbuf -> soft mask; read img + sharp16; final -> outp.
#define FW 64
#define HC 128
#define VROWS 178    // HC + 2*RR

template<int MODE>
__global__ __launch_bounds__(256) void k_vconv(const __half* __restrict__ src,
                                               const float* __restrict__ img,
                                               __half* __restrict__ sharp16,
                                               float* __restrict__ outp,
                                               unsigned char* __restrict__ mask8,
                                               const float* __restrict__ gsrc) {
    __shared__ __align__(16) float tile[VROWS * FW];
    const int t  = threadIdx.x;
    const int cg = t & 15;               // col group: cols 4*cg..4*cg+3
    const int rg = t >> 4;               // row group: rows rg*8..rg*8+7
    const int bid = blockIdx.x;
    const int wcB = bid % 24;
    const int hB  = (bid / 24) & 3;
    const int b   = bid / 96;
    const int wc0 = wcB * 64;
    const int h0  = hB * HC;

    float gw[KK];
    #pragma unroll
    for (int i = 0; i < KK; ++i) gw[i] = gsrc[i];

    const size_t imgbase = (size_t)b * HH * ROWLEN;

    // ---- load tile (178 rows x 16 chunks of 4) with reflect on h ----
    #pragma unroll
    for (int i = 0; i < 12; ++i) {
        const int m = t + 256 * i;
        if (m < VROWS * 16) {
            const int r = m >> 4, cc = m & 15;
            int hs = h0 - RR + r;
            hs = hs < 0 ? -hs : hs;
            hs = hs > 511 ? 1022 - hs : hs;
            const __half2* sp = (const __half2*)&src[imgbase + (size_t)hs * ROWLEN + wc0 + 4 * cc];
            const float2 fa = __half22float2(sp[0]);
            const float2 fb = __half22float2(sp[1]);
            float4 o; o.x = fa.x; o.y = fa.y; o.z = fb.x; o.w = fb.y;
            *(float4*)&tile[r * FW + 4 * cc] = o;
        }
    }
    __syncthreads();

    float acc[8][4];
    #pragma unroll
    for (int a = 0; a < 8; ++a)
        #pragma unroll
        for (int m = 0; m < 4; ++m) acc[a][m] = 0.f;

    const float* base = &tile[(rg * 8) * FW + 4 * cg];
    #pragma unroll
    for (int jj = 0; jj < 58; ++jj) {
        const float4 v4 = *(const float4*)(base + jj * FW);
        #pragma unroll
        for (int a = 0; a < 8; ++a) {
            const int tap = jj - a;
            if (tap >= 0 && tap < KK) {
                acc[a][0] += gw[tap] * v4.x;
                acc[a][1] += gw[tap] * v4.y;
                acc[a][2] += gw[tap] * v4.z;
                acc[a][3] += gw[tap] * v4.w;
            }
        }
    }

    // ---- fused epilogue ----
    #pragma unroll
    for (int a = 0; a < 8; ++a) {
        const int hh = h0 + rg * 8 + a;
        const size_t idx = imgbase + (size_t)hh * ROWLEN + wc0 + 4 * cg;
        const float4 x4 = *(const float4*)&img[idx];
        const float* xp = &x4.x;
        if (MODE == 0) {
            float sh[4];
            unsigned int mw = 0;
            #pragma unroll
            for (int m = 0; m < 4; ++m) {
                const float x = xp[m];
                const float res = x - acc[a][m];
                sh[m] = fminf(fmaxf(x + 0.5f * res, 0.f), 1.f);
                if (fabsf(res) * 255.0f > 10.0f) mw |= (1u << (8 * m));
            }
            *(__half2*)&sharp16[idx]     = __floats2half2_rn(sh[0], sh[1]);
            *(__half2*)&sharp16[idx + 2] = __floats2half2_rn(sh[2], sh[3]);
            *(unsigned int*)&mask8[idx] = mw;
        } else {
            const __half2 sa = *(const __half2*)&sharp16[idx];
            const __half2 sb = *(const __half2*)&sharp16[idx + 2];
            const float2 f0 = __half22float2(sa);
            const float2 f1 = __half22float2(sb);
            const float shv[4] = {f0.x, f0.y, f1.x, f1.y};
            float4 o; float* op = &o.x;
            #pragma unroll
            for (int m = 0; m < 4; ++m) {
                const float x = xp[m];
                op[m] = x + acc[a][m] * (shv[m] - x);
            }
            *(float4*)&outp[idx] = o;
        }
    }
}

// ---------------------------------------------------------------------------
extern "C" void kernel_launch(void* const* d_in, const int* in_sizes, int n_in,
                              void* d_out, int out_size, void* d_ws, size_t ws_size,
                              hipStream_t stream) {
    (void)in_sizes; (void)n_in; (void)out_size; (void)ws_size;
    const float* img = (const float*)d_in[0];
    const float* k2d = (const float*)d_in[1];
    float* out = (float*)d_out;

    const size_t NPX = (size_t)BB * HH * ROWLEN;   // 12.58M flats
    char* ws = (char*)d_ws;
    float* g = (float*)ws;                          // 51 floats (256B slot)
    __half* tbuf = (__half*)(ws + 256);             // 25.2 MB
    unsigned char* mask8 = (unsigned char*)(ws + 256 + NPX * 2);      // 12.6 MB
    __half* sharp16 = (__half*)(ws + 256 + NPX * 2 + NPX);            // 25.2 MB

    const int nhblk = BB * HH / 4;        // 2048
    const int nvblk = BB * 4 * 24;        // 1536

    k_weights<<<1, 64, 0, stream>>>(k2d, g);
    // P1: H-blur img -> tbuf (fp16)
    k_hconv<false><<<nhblk, 512, 0, stream>>>((const void*)img, tbuf, g);
    // P2: V-blur tbuf -> blur (regs); sharp16 + mask8 out
    k_vconv<0><<<nvblk, 256, 0, stream>>>(tbuf, img, sharp16, out, mask8, g);
    // P3: H-blur mask8 -> tbuf (fp16)
    k_hconv<true><<<nhblk, 512, 0, stream>>>((const void*)mask8, tbuf, g);
    // P4: V-blur tbuf -> soft mask; blend img/sharp16 -> d_out
    k_vconv<1><<<nvblk, 256, 0, stream>>>(tbuf, img, sharp16, out, mask8, g);
}